// Round 8
// baseline (373.095 us; speedup 1.0000x reference)
//
#include <hip/hip_runtime.h>

#define ALPHA_MIN 0.8187307530779818f  // exp(-1/5)
#define ALPHA_MAX 0.9607894391523232f  // exp(-1/25)

typedef _Float16 f16;
typedef _Float16 f16x8 __attribute__((ext_vector_type(8)));
typedef float f32x16 __attribute__((ext_vector_type(16)));

// Fixed problem shape
#define BB_ 32
#define TT_ 2048
#define KK_ 256
#define HH_ 512

// ---- async global->LDS, 16 B per lane (m97 recipe) -------------------------
__device__ __forceinline__ void gll16(const float* g, float* l) {
    __builtin_amdgcn_global_load_lds(
        (const __attribute__((address_space(1))) void*)g,
        (__attribute__((address_space(3))) void*)l, 16, 0, 0);
}

// ---- fp32 -> (hi, lo*2048) f16 pair, 8 elems -------------------------------
__device__ __forceinline__ void cvt8(const float4 v0, const float4 v1,
                                     f16x8& h, f16x8& l) {
    const float v[8] = {v0.x, v0.y, v0.z, v0.w, v1.x, v1.y, v1.z, v1.w};
#pragma unroll
    for (int j = 0; j < 8; ++j) {
        const f16 hj = (f16)v[j];
        h[j] = hj;
        l[j] = (f16)((v[j] - (float)hj) * 2048.0f);
    }
}

// ============ GEMM: C[M,N] = X[M,K]*W[N,K]^T, m97-style staging =============
// Tile 128x128, BK=32, 256 thr = 4 waves, wave = 64x64 via 2x2 of
// v_mfma_f32_32x32x16_f16, fp16-split (3 MFMA passes, Al*Bl dropped).
// Staging: raw fp32 tiles via global_load_lds width=16 (no VGPR round trip).
// LDS unpadded (required); 16B-group XOR-swizzle by row applied on the
// GLOBAL gather side so ds_read_b128 fragment reads are <=2-way conflicts.
// Convert-on-read: fp32 frags -> hi/lo f16 in VALU, co-issues with MFMA.
__global__ __launch_bounds__(256) void gemm_lds(
    const float* __restrict__ X,   // (M,K)
    const float* __restrict__ W,   // (N,K)
    float* __restrict__ C,         // (M,N)
    int M, int N, int K)
{
    __shared__ float As[128 * 32];   // 16 KB, row-major 128x32, swizzled groups
    __shared__ float Bs[128 * 32];   // 16 KB

    const int tid = threadIdx.x;
    const int mt = blockIdx.x >> 2;       // 4 n-tiles adjacent -> A reuse in L3
    const int nt = blockIdx.x & 3;
    const int m0 = mt * 128, n0 = nt * 128;

    const int lane = tid & 63;
    const int wv   = tid >> 6;            // wave 0..3
    const int wm   = wv & 1;
    const int wn   = wv >> 1;
    const int fm   = lane & 31;
    const int fq   = lane >> 5;

    // staging decomposition: lane -> (row-in-8, group-slot)
    const int rA  = lane >> 3;            // 0..7
    const int gq  = lane & 7;             // LDS 16B-group slot
    const int gsw = gq ^ rA;              // swizzled global group to fetch

    f32x16 accH[2][2], accL[2][2];
#pragma unroll
    for (int i = 0; i < 2; ++i)
#pragma unroll
        for (int j = 0; j < 2; ++j)
#pragma unroll
            for (int e = 0; e < 16; ++e) { accH[i][j][e] = 0.0f; accL[i][j][e] = 0.0f; }

    const int KT = K / 32;                // 8
    for (int kt = 0; kt < KT; ++kt) {
        // ---- stage: 8 global_load_lds (1 KB each) per wave ----
#pragma unroll
        for (int j = 0; j < 4; ++j) {
            const int row = wv * 32 + j * 8 + rA;
            gll16(&X[(size_t)(m0 + row) * K + kt * 32 + gsw * 4],
                  &As[(wv * 32 + j * 8) * 32]);
            gll16(&W[(size_t)(n0 + row) * K + kt * 32 + gsw * 4],
                  &Bs[(wv * 32 + j * 8) * 32]);
        }
        __syncthreads();   // drains vmcnt (global_load_lds) before ds_read

        // ---- compute: convert-on-read + 12 MFMA per ks ----
#pragma unroll
        for (int ks = 0; ks < 2; ++ks) {
            const int G = ks * 4 + fq * 2;       // even 16B-group index
            f16x8 ah[2], al[2], bh[2], bl[2];
#pragma unroll
            for (int mb = 0; mb < 2; ++mb) {
                const int row = wm * 64 + mb * 32 + fm;
                const int r7 = row & 7;
                const float4 a0 = *(const float4*)&As[row * 32 + ((G    ) ^ r7) * 4];
                const float4 a1 = *(const float4*)&As[row * 32 + ((G + 1) ^ r7) * 4];
                cvt8(a0, a1, ah[mb], al[mb]);
            }
#pragma unroll
            for (int nb = 0; nb < 2; ++nb) {
                const int row = wn * 64 + nb * 32 + fm;
                const int r7 = row & 7;
                const float4 b0 = *(const float4*)&Bs[row * 32 + ((G    ) ^ r7) * 4];
                const float4 b1 = *(const float4*)&Bs[row * 32 + ((G + 1) ^ r7) * 4];
                cvt8(b0, b1, bh[nb], bl[nb]);
            }
#pragma unroll
            for (int mb = 0; mb < 2; ++mb)
#pragma unroll
                for (int nb = 0; nb < 2; ++nb) {
                    accH[mb][nb] = __builtin_amdgcn_mfma_f32_32x32x16_f16(ah[mb], bh[nb], accH[mb][nb], 0, 0, 0);
                    accL[mb][nb] = __builtin_amdgcn_mfma_f32_32x32x16_f16(ah[mb], bl[nb], accL[mb][nb], 0, 0, 0);
                    accL[mb][nb] = __builtin_amdgcn_mfma_f32_32x32x16_f16(al[mb], bh[nb], accL[mb][nb], 0, 0, 0);
                }
        }
        __syncthreads();
    }

    // ---- epilogue: C = accH + accL * 2^-11 ----
    // C/D layout: col = lane&31, row = (r&3) + 8*(r>>2) + 4*(lane>>5)
#pragma unroll
    for (int mb = 0; mb < 2; ++mb)
#pragma unroll
        for (int nb = 0; nb < 2; ++nb) {
            const int col   = n0 + wn * 64 + nb * 32 + fm;
            const int rbase = m0 + wm * 64 + mb * 32 + 4 * fq;
#pragma unroll
            for (int g = 0; g < 4; ++g)
#pragma unroll
                for (int r = 0; r < 4; ++r) {
                    const int row = rbase + 8 * g + r;
                    C[(size_t)row * N + col] = accH[mb][nb][4 * g + r]
                                             + accL[mb][nb][4 * g + r] * (1.0f / 2048.0f);
                }
        }
}

// ---------------- LIF scan, wx (ws) -> spikes (out), alias-free -------------
#define SU 64

__global__ __launch_bounds__(64) void lif_scan2(
    const float* __restrict__ wx,       // (B,T,H)
    float* __restrict__ out,            // (B,T,H)
    const float* __restrict__ alpha,
    const float* __restrict__ u0,
    const float* __restrict__ s0,
    int T, int H)
{
    const int chain = blockIdx.x * 64 + threadIdx.x;
    const int h = chain % H;
    const int b = chain / H;

    float a = alpha[h];
    a = fminf(fmaxf(a, ALPHA_MIN), ALPHA_MAX);
    const float bb = 1.0f - a;

    float u = u0[chain];
    float s = s0[chain];

    const float* src = wx + (size_t)b * T * H + h;
    float* dst = out + (size_t)b * T * H + h;

    float w0[SU], w1[SU];
#pragma unroll
    for (int j = 0; j < SU; ++j) w0[j] = src[(size_t)j * H];

    const int NC = T / SU;               // 32 (even)
    for (int c = 0; c < NC; c += 2) {
#pragma unroll
        for (int j = 0; j < SU; ++j) w1[j] = src[(size_t)((c + 1) * SU + j) * H];
#pragma unroll
        for (int j = 0; j < SU; ++j) {
            u = fmaf(a, u - s, bb * w0[j]);
            s = (u > 1.0f) ? 1.0f : 0.0f;
            __builtin_nontemporal_store(s, &dst[(size_t)(c * SU + j) * H]);
        }
        if (c + 2 < NC) {
#pragma unroll
            for (int j = 0; j < SU; ++j) w0[j] = src[(size_t)((c + 2) * SU + j) * H];
        }
#pragma unroll
        for (int j = 0; j < SU; ++j) {
            u = fmaf(a, u - s, bb * w1[j]);
            s = (u > 1.0f) ? 1.0f : 0.0f;
            __builtin_nontemporal_store(s, &dst[(size_t)((c + 1) * SU + j) * H]);
        }
    }
}

// ---------------- fallbacks -------------------------------------------------
__global__ void gemm_naive(const float* __restrict__ X, const float* __restrict__ W,
                           float* __restrict__ C, int M, int N, int K)
{
    const int idx = blockIdx.x * 256 + threadIdx.x;
    if (idx >= M * N) return;
    const int m = idx / N, n = idx % N;
    float acc = 0.0f;
    for (int k = 0; k < K; ++k) acc = fmaf(X[(size_t)m * K + k], W[(size_t)n * K + k], acc);
    C[idx] = acc;
}

__global__ __launch_bounds__(64) void lif_scan_inplace(
    float* __restrict__ buf, const float* __restrict__ alpha,
    const float* __restrict__ u0, const float* __restrict__ s0, int T, int H)
{
    const int chain = blockIdx.x * 64 + threadIdx.x;
    const int h = chain % H;
    const int b = chain / H;
    float a = alpha[h];
    a = fminf(fmaxf(a, ALPHA_MIN), ALPHA_MAX);
    const float bb = 1.0f - a;
    float u = u0[chain], s = s0[chain];
    float* base = buf + (size_t)b * T * H + h;
    for (int t = 0; t < T; ++t) {
        u = fmaf(a, u - s, bb * base[(size_t)t * H]);
        s = (u > 1.0f) ? 1.0f : 0.0f;
        base[(size_t)t * H] = s;
    }
}

// ---------------- launch ----------------------------------------------------
extern "C" void kernel_launch(void* const* d_in, const int* in_sizes, int n_in,
                              void* d_out, int out_size, void* d_ws, size_t ws_size,
                              hipStream_t stream) {
    const float* x     = (const float*)d_in[0];
    const float* W     = (const float*)d_in[1];
    const float* alpha = (const float*)d_in[2];
    const float* u0    = (const float*)d_in[3];
    const float* s0    = (const float*)d_in[4];
    float* out = (float*)d_out;

    const int H = in_sizes[2];
    const int I = in_sizes[1] / H;
    const int B = in_sizes[3] / H;
    const int T = in_sizes[0] / (B * I);
    const int M = B * T;

    const size_t szWx = (size_t)M * H * sizeof(float);

    if (B == BB_ && T == TT_ && I == KK_ && H == HH_ && ws_size >= szWx) {
        float* Wx = (float*)d_ws;
        gemm_lds<<<(M / 128) * (H / 128), 256, 0, stream>>>(x, W, Wx, M, H, I);
        lif_scan2<<<(B * H) / 64, 64, 0, stream>>>(Wx, out, alpha, u0, s0, T, H);
    } else {
        gemm_naive<<<(M * H + 255) / 256, 256, 0, stream>>>(x, W, out, M, H, I);
        lif_scan_inplace<<<(B * H + 63) / 64, 64, 0, stream>>>(out, alpha, u0, s0, T, H);
    }
}

// Round 9
// 280.627 us; speedup vs baseline: 1.3295x; 1.3295x over previous
//
#include <hip/hip_runtime.h>

#define ALPHA_MIN 0.8187307530779818f  // exp(-1/5)
#define ALPHA_MAX 0.9607894391523232f  // exp(-1/25)

typedef _Float16 f16;
typedef _Float16 f16x4 __attribute__((ext_vector_type(4)));
typedef _Float16 f16x8 __attribute__((ext_vector_type(8)));
typedef float f32x16 __attribute__((ext_vector_type(16)));

// Fixed problem shape
#define BB_ 32
#define TT_ 2048
#define KK_ 256
#define HH_ 512
#define TC_ 64               // timesteps per chunk
#define NC_ 32               // chunks
#define KH_ 128              // k-half (two halves of K=256)

// Barrier WITHOUT vmcnt drain: waits LDS ops only, leaves global loads in
// flight across the barrier (AITER-style). imm 0xC07F = vmcnt(63) expcnt(7)
// lgkmcnt(0) on gfx9 encoding.
__device__ __forceinline__ void barrier_lds() {
    __builtin_amdgcn_s_waitcnt(0xC07F);
    __builtin_amdgcn_s_barrier();
}

// ============================ fused kernel ==================================
// grid 256 = (nt<<5)|b -> XCD = b%8: the 8 n-panel blocks of batch b share
// X[b] (2 MB) in one XCD L2 (R5-verified: FETCH 35 MB).
// block 320 = 5 waves: 4 GEMM (one 32x32 mfma tile each) + 1 LIF-scan wave.
// Per chunk (64 t), two k-halves; per half:
//   P_cvt : convert prefetched X regs -> hi/lo f16 in swizzled LDS; issue
//           next half's coalesced loads (2 rows x 512 B per instr)
//   P_mma : 8 x (2 ds_read_b128 + 3 MFMA), zero convert VALU in loop;
//           scan wave consumes chunk c-1 from wxbuf concurrently.
// fp16-split: C = Ah*Bh + 2^-11*(Ah*Bl + Al*Bh); B-panel in registers.
__global__ __launch_bounds__(320, 1) void lif_fused4(
    const float* __restrict__ X,      // (B,T,K)
    const float* __restrict__ W,      // (H,K)
    const float* __restrict__ alpha,  // (H)
    const float* __restrict__ u0,     // (B,H)
    const float* __restrict__ s0,     // (B,H)
    float* __restrict__ out)          // (B,T,H)
{
    __shared__ f16 Ah[TC_ * KH_];            // 16 KB (swizzled 8-f16 groups)
    __shared__ f16 Al[TC_ * KH_];            // 16 KB
    __shared__ float wxbuf[2][TC_ * 64];     // 32 KB

    const int b  = blockIdx.x & 31;
    const int nt = blockIdx.x >> 5;
    const int n0 = nt * 64;

    const int tid  = threadIdx.x;
    const int wv   = tid >> 6;               // 0..4
    const int lane = tid & 63;
    const int fm   = lane & 31;
    const int fq   = lane >> 5;

    if (wv < 4) {
        // ========================= GEMM waves ==============================
        const int mh = wv >> 1;              // t-half of chunk tile
        const int nh = wv & 1;               // n-half of panel

        // ---- B prologue: W[n0+nh*32+fm][:] -> hi/lo f16 register frags ----
        f16x8 bh[16], bl[16];
        {
            const float* wp = W + (size_t)(n0 + nh * 32 + fm) * KK_ + fq * 8;
#pragma unroll
            for (int ks = 0; ks < 16; ++ks) {
                float4 v0 = *(const float4*)(wp + ks * 16);
                float4 v1 = *(const float4*)(wp + ks * 16 + 4);
                float v[8] = {v0.x, v0.y, v0.z, v0.w, v1.x, v1.y, v1.z, v1.w};
                f16x8 h, l;
#pragma unroll
                for (int j = 0; j < 8; ++j) {
                    const f16 hj = (f16)v[j];
                    h[j] = hj;
                    l[j] = (f16)((v[j] - (float)hj) * 2048.0f);
                }
                bh[ks] = h; bl[ks] = l;
            }
        }

        f32x16 accH, accLa, accLb;
#pragma unroll
        for (int e = 0; e < 16; ++e) { accH[e] = 0.0f; accLa[e] = 0.0f; accLb[e] = 0.0f; }

        // staging lane mapping: instr j covers rows wv*16+j*2+{0,1},
        // 32 lanes x 16 B = one contiguous 512 B k-half row  -> coalesced
        const int srow_j = wv * 16 + (lane >> 5);   // + j*2
        const int f4i    = lane & 31;
        const int g      = f4i >> 1;                // 8-f16 group 0..15
        const int sub    = f4i & 1;

        float4 pend[8];
        auto issue_loads = [&](int c, int kh) {
            const float* base = X + ((size_t)b * TT_ + c * TC_) * KK_ + kh * KH_ + f4i * 4;
#pragma unroll
            for (int j = 0; j < 8; ++j)
                pend[j] = *(const float4*)(base + (size_t)(srow_j + j * 2) * KK_);
        };
        auto cvt_write = [&]() {
#pragma unroll
            for (int j = 0; j < 8; ++j) {
                const int row = srow_j + j * 2;
                const float v[4] = {pend[j].x, pend[j].y, pend[j].z, pend[j].w};
                f16x4 h, l;
#pragma unroll
                for (int e = 0; e < 4; ++e) {
                    const f16 he = (f16)v[e];
                    h[e] = he;
                    l[e] = (f16)((v[e] - (float)he) * 2048.0f);
                }
                const int addr = row * KH_ + ((g ^ (row & 15)) * 8) + sub * 4;
                *(f16x4*)&Ah[addr] = h;
                *(f16x4*)&Al[addr] = l;
            }
        };
        auto compute_half = [&](int hf) {
            const int row = mh * 32 + fm;
            const int r15 = row & 15;
#pragma unroll
            for (int ks = 0; ks < 8; ++ks) {
                const int addr = row * KH_ + (((ks * 2 + fq) ^ r15) * 8);
                const f16x8 ah = *(const f16x8*)&Ah[addr];
                const f16x8 al = *(const f16x8*)&Al[addr];
                const int ksg = hf * 8 + ks;
                accH  = __builtin_amdgcn_mfma_f32_32x32x16_f16(ah, bh[ksg], accH,  0, 0, 0);
                accLa = __builtin_amdgcn_mfma_f32_32x32x16_f16(ah, bl[ksg], accLa, 0, 0, 0);
                accLb = __builtin_amdgcn_mfma_f32_32x32x16_f16(al, bh[ksg], accLb, 0, 0, 0);
            }
        };

        issue_loads(0, 0);

        for (int c = 0; c < NC_; ++c) {
            // P1: materialize kh0; prefetch kh1
            cvt_write();
            issue_loads(c, 1);
            barrier_lds();
            // P2: MFMA on kh0   (scan consumes chunk c-1 concurrently)
            compute_half(0);
            barrier_lds();
            // P3: materialize kh1; prefetch next chunk kh0
            cvt_write();
            if (c + 1 < NC_) issue_loads(c + 1, 0);
            barrier_lds();
            // P4: MFMA on kh1 + epilogue -> wxbuf[c&1]
            compute_half(1);
            {
                float* wb = &wxbuf[c & 1][0];
                const int colw = nh * 32 + fm;
#pragma unroll
                for (int r = 0; r < 16; ++r) {
                    const int roww = mh * 32 + (r & 3) + 8 * (r >> 2) + 4 * fq;
                    wb[roww * 64 + colw] = accH[r] + (accLa[r] + accLb[r]) * (1.0f / 2048.0f);
                    accH[r] = 0.0f; accLa[r] = 0.0f; accLb[r] = 0.0f;
                }
            }
            barrier_lds();
        }
    } else {
        // ========================= scan wave ===============================
        const int h = n0 + lane;
        const int chain = b * HH_ + h;
        float a = alpha[h];
        a = fminf(fmaxf(a, ALPHA_MIN), ALPHA_MAX);
        const float bbv = 1.0f - a;
        float u = u0[chain];
        float s = s0[chain];
        float* op = out + (size_t)b * TT_ * HH_ + h;

        auto consume = [&](int c, int hf) {
            const float* wb = &wxbuf[c & 1][0];
            const int tb = c * TC_ + hf * 32;
#pragma unroll
            for (int t0 = 0; t0 < 32; t0 += 8) {
                float w[8];
#pragma unroll
                for (int j = 0; j < 8; ++j) w[j] = wb[(hf * 32 + t0 + j) * 64 + lane];
#pragma unroll
                for (int j = 0; j < 8; ++j) {
                    u = fmaf(a, u - s, bbv * w[j]);
                    s = (u > 1.0f) ? 1.0f : 0.0f;
                    __builtin_nontemporal_store(s, &op[(size_t)(tb + t0 + j) * HH_]);
                }
            }
        };

        for (int c = 0; c < NC_; ++c) {
            barrier_lds();                       // P1 end
            if (c > 0) consume(c - 1, 0);        // overlap P2
            barrier_lds();                       // P2 end
            barrier_lds();                       // P3 end
            if (c > 0) consume(c - 1, 1);        // overlap P4
            barrier_lds();                       // P4 end
        }
        consume(NC_ - 1, 0);
        consume(NC_ - 1, 1);
    }
}

// =================== generic fallback (non-reference shapes) ================
__global__ void gemm_naive(const float* __restrict__ X, const float* __restrict__ W,
                           float* __restrict__ C, int M, int N, int K)
{
    const int idx = blockIdx.x * 256 + threadIdx.x;
    if (idx >= M * N) return;
    const int m = idx / N, n = idx % N;
    float acc = 0.0f;
    for (int k = 0; k < K; ++k) acc = fmaf(X[(size_t)m * K + k], W[(size_t)n * K + k], acc);
    C[idx] = acc;
}

__global__ __launch_bounds__(64) void lif_scan_inplace(
    float* __restrict__ buf, const float* __restrict__ alpha,
    const float* __restrict__ u0, const float* __restrict__ s0, int T, int H)
{
    const int chain = blockIdx.x * 64 + threadIdx.x;
    const int h = chain % H;
    const int b = chain / H;
    float a = alpha[h];
    a = fminf(fmaxf(a, ALPHA_MIN), ALPHA_MAX);
    const float bb = 1.0f - a;
    float u = u0[chain], s = s0[chain];
    float* base = buf + (size_t)b * T * H + h;
    for (int t = 0; t < T; ++t) {
        u = fmaf(a, u - s, bb * base[(size_t)t * H]);
        s = (u > 1.0f) ? 1.0f : 0.0f;
        base[(size_t)t * H] = s;
    }
}

// ---------------- launch ----------------------------------------------------
extern "C" void kernel_launch(void* const* d_in, const int* in_sizes, int n_in,
                              void* d_out, int out_size, void* d_ws, size_t ws_size,
                              hipStream_t stream) {
    const float* x     = (const float*)d_in[0];
    const float* W     = (const float*)d_in[1];
    const float* alpha = (const float*)d_in[2];
    const float* u0    = (const float*)d_in[3];
    const float* s0    = (const float*)d_in[4];
    float* out = (float*)d_out;

    const int H = in_sizes[2];
    const int I = in_sizes[1] / H;
    const int B = in_sizes[3] / H;
    const int T = in_sizes[0] / (B * I);

    if (B == BB_ && T == TT_ && I == KK_ && H == HH_) {
        lif_fused4<<<256, 320, 0, stream>>>(x, W, alpha, u0, s0, out);
    } else {
        const int M = B * T;
        gemm_naive<<<(M * H + 255) / 256, 256, 0, stream>>>(x, W, out, M, H, I);
        lif_scan_inplace<<<(B * H + 63) / 64, 64, 0, stream>>>(out, alpha, u0, s0, T, H);
    }
}